// Round 4
// baseline (102.626 us; speedup 1.0000x reference)
//
#include <hip/hip_runtime.h>
#include <hip/hip_bf16.h>

// ToneMappingCurveLoss: luma-binned mean-difference loss.
// Inputs: pred, target, input_img: [16, 3, 512, 512] f32. Output: 1 f32 scalar.
// HW = 512*512 = 262144 ; float4 groups per channel = 65536 = 2^16.

#define CH4 65536         // HW/4
#define NBINS 16
#define NCOL (3 * NBINS)  // 48 columns: count, psum, tsum per bin
#define COPIES 64         // per-lane privatized histogram copies

__device__ __forceinline__ float luma_exact(float r, float g, float b) {
    // match numpy/jax f32 evaluation order, no FMA contraction
    return __fadd_rn(__fadd_rn(__fmul_rn(0.299f, r), __fmul_rn(0.587f, g)),
                     __fmul_rn(0.114f, b));
}

__global__ __launch_bounds__(256) void tm_stage1(
    const float4* __restrict__ pred,
    const float4* __restrict__ target,
    const float4* __restrict__ input,
    float* __restrict__ partials,   // column-major [NCOL][rows]
    int G, int rows)
{
    __shared__ float h[NCOL * COPIES];   // 12 KB, per-lane copies
    const int t = threadIdx.x;
    const int lane = t & 63;

    for (int i = t; i < NCOL * COPIES; i += 256) h[i] = 0.0f;
    __syncthreads();

    const int T = gridDim.x * 256;      // group stride (524288 at this shape)
    int g = blockIdx.x * 256 + t;

    // ---- software pipeline: double-buffered 9-load batches ----
    float4 ci0, ci1, ci2, cp0, cp1, cp2, ct0, ct1, ct2;
    bool valid = (g < G);
    if (valid) {
        const int a = (g >> 16) * (3 * CH4) + (g & (CH4 - 1));
        ci0 = input[a];  ci1 = input[a + CH4];  ci2 = input[a + 2 * CH4];
        cp0 = pred[a];   cp1 = pred[a + CH4];   cp2 = pred[a + 2 * CH4];
        ct0 = target[a]; ct1 = target[a + CH4]; ct2 = target[a + 2 * CH4];
    }

    while (valid) {
        const int gn = g + T;
        const bool vn = (gn < G);
        float4 ni0, ni1, ni2, np0, np1, np2, nt0, nt1, nt2;
        if (vn) {       // issue next batch BEFORE consuming current
            const int a = (gn >> 16) * (3 * CH4) + (gn & (CH4 - 1));
            ni0 = input[a];  ni1 = input[a + CH4];  ni2 = input[a + 2 * CH4];
            np0 = pred[a];   np1 = pred[a + CH4];   np2 = pred[a + 2 * CH4];
            nt0 = target[a]; nt1 = target[a + CH4]; nt2 = target[a + 2 * CH4];
        }

        // consume current batch
        {
            const float ir[4] = {ci0.x, ci0.y, ci0.z, ci0.w};
            const float ig[4] = {ci1.x, ci1.y, ci1.z, ci1.w};
            const float ib[4] = {ci2.x, ci2.y, ci2.z, ci2.w};
            const float pr[4] = {cp0.x, cp0.y, cp0.z, cp0.w};
            const float pg[4] = {cp1.x, cp1.y, cp1.z, cp1.w};
            const float pb[4] = {cp2.x, cp2.y, cp2.z, cp2.w};
            const float tr[4] = {ct0.x, ct0.y, ct0.z, ct0.w};
            const float tg[4] = {ct1.x, ct1.y, ct1.z, ct1.w};
            const float tb[4] = {ct2.x, ct2.y, ct2.z, ct2.w};

            #pragma unroll
            for (int j = 0; j < 4; ++j) {
                const float il = luma_exact(ir[j], ig[j], ib[j]);
                if (il < 1.0f) {
                    int bin = (int)floorf(__fmul_rn(il, 16.0f));
                    bin = min(max(bin, 0), NBINS - 1);
                    const float pl = luma_exact(pr[j], pg[j], pb[j]);
                    const float tl = luma_exact(tr[j], tg[j], tb[j]);
                    atomicAdd(&h[bin * COPIES + lane], 1.0f);
                    atomicAdd(&h[(NBINS + bin) * COPIES + lane], pl);
                    atomicAdd(&h[(2 * NBINS + bin) * COPIES + lane], tl);
                }
            }
        }

        // rotate buffers
        ci0 = ni0; ci1 = ni1; ci2 = ni2;
        cp0 = np0; cp1 = np1; cp2 = np2;
        ct0 = nt0; ct1 = nt1; ct2 = nt2;
        g = gn; valid = vn;
    }

    __syncthreads();
    // Block epilogue: 4 waves each reduce 12 columns over the 64 lane-copies.
    const int w = t >> 6;
    #pragma unroll
    for (int k = 0; k < 12; ++k) {
        const int c = w * 12 + k;
        float v = h[c * COPIES + lane];
        v += __shfl_down(v, 32);
        v += __shfl_down(v, 16);
        v += __shfl_down(v, 8);
        v += __shfl_down(v, 4);
        v += __shfl_down(v, 2);
        v += __shfl_down(v, 1);
        if (lane == 0) partials[c * rows + blockIdx.x] = v;
    }
}

__global__ __launch_bounds__(768) void tm_stage2(
    const float4* __restrict__ partials4,  // column-major [NCOL][rows/4] float4
    float* __restrict__ out, int rows4)
{
    __shared__ double col[NCOL];
    const int t = threadIdx.x;          // 768 = 48 cols x 16 threads
    const int c = t >> 4;
    const int l = t & 15;

    double s = 0.0;
    for (int k = l; k < rows4; k += 16) {
        const float4 v = partials4[c * rows4 + k];
        s += (double)v.x + (double)v.y + (double)v.z + (double)v.w;
    }
    #pragma unroll
    for (int k = 8; k; k >>= 1) s += __shfl_down(s, k, 16);
    if (l == 0) col[c] = s;
    __syncthreads();

    if (t == 0) {
        double acc = 0.0;
        #pragma unroll
        for (int i = 0; i < NBINS; ++i) {
            const double cnt = col[i];
            if (cnt > 0.0) {
                acc += fabs(col[NBINS + i] / cnt - col[2 * NBINS + i] / cnt);
            }
        }
        out[0] = (float)(acc / (double)NBINS);
    }
}

extern "C" void kernel_launch(void* const* d_in, const int* in_sizes, int n_in,
                              void* d_out, int out_size, void* d_ws, size_t ws_size,
                              hipStream_t stream) {
    const float* pred   = (const float*)d_in[0];
    const float* target = (const float*)d_in[1];
    const float* input  = (const float*)d_in[2];

    // in_sizes[0] = B*3*H*W ; pixel float4-groups = size / (3*4)
    const int G = in_sizes[0] / 12;

    // 2048 blocks (8/CU nominal) -> each thread pipelines exactly 2 groups.
    int blocks = 2048;
    const size_t maxRows = ws_size / (NCOL * sizeof(float));
    if ((size_t)blocks > maxRows) blocks = (int)maxRows;
    if (blocks < 1) blocks = 1;
    const int rows = (blocks + 3) & ~3;   // pad to multiple of 4 for float4 stage2

    tm_stage1<<<blocks, 256, 0, stream>>>(
        (const float4*)pred, (const float4*)target, (const float4*)input,
        (float*)d_ws, G, rows);
    tm_stage2<<<1, 768, 0, stream>>>((const float4*)d_ws, (float*)d_out, rows / 4);
}